// Round 1
// 10318.285 us; speedup vs baseline: 1.0232x; 1.0232x over previous
//
#include <hip/hip_runtime.h>
#include <math.h>

namespace {

constexpr int B = 256, T = 64, ACTN = 6, EMB = 1024;
constexpr int S = 32, DD = 32, SFN = 1024;   // stoch groups, classes, flat
constexpr int DET = 600, HID = 600;
constexpr int OUTF = 4 * SFN + DET;          // 4696

__device__ __forceinline__ float elu1(float x) { return x > 0.f ? x : expm1f(x); }
__device__ __forceinline__ float sigm(float x) { return 1.f / (1.f + expf(-x)); }

// XCD-pinned jg mapping: 75 jg groups split 10,10,10,9,9,9,9,9 across the 8 XCDs
// (bid%8 -> XCD assumed round-robin; consistent across launches is what matters).
// All 4 rg replicas of a jg slice land on the SAME XCD -> weights stay L2-resident
// across the 64 timestep launches.
__device__ __forceinline__ bool jgMap(int bid, int& jg, int& rg) {
    int xcd = bid & 7, slot = bid >> 3;   // grid = 320
    int jgLocal = slot >> 2;
    rg = slot & 3;
    int cnt = (xcd < 3) ? 10 : 9;
    if (jgLocal >= cnt) return false;
    jg = ((xcd < 3) ? xcd * 10 : 30 + (xcd - 3) * 9) + jgLocal;
    return true;
}

// ---------------- weight prep: fused/transposed layouts ----------------
// WB[j][k][3] : k<600 from Wx, k>=600 from Wh; triple = (z, r, h) columns j, 600+j, 1200+j
__global__ void kWB(const float* __restrict__ Wx, const float* __restrict__ Wh,
                    float* __restrict__ WBm) {
    int k = blockIdx.x;  // 0..1199
    const float* src = (k < 600) ? (Wx + (size_t)k * 1800) : (Wh + (size_t)(k - 600) * 1800);
    for (int j = threadIdx.x; j < 600; j += blockDim.x) {
        size_t o = ((size_t)j * 1200 + k) * 3;
        WBm[o + 0] = src[j];
        WBm[o + 1] = src[600 + j];
        WBm[o + 2] = src[1200 + j];
    }
}

// WC[j][k] : j<600 -> W_img2[k][j] ; j>=600 -> W_obs1[k][j-600] (deter rows 0..599)
__global__ void kWC(const float* __restrict__ W2, const float* __restrict__ Wo1,
                    float* __restrict__ WCm) {
    int k = blockIdx.x;  // 0..599
    for (int j = threadIdx.x; j < 1200; j += blockDim.x) {
        float v = (j < 600) ? W2[(size_t)k * 600 + j] : Wo1[(size_t)k * 600 + (j - 600)];
        WCm[(size_t)j * 600 + k] = v;
    }
}

// WD[j][k] : j<1024 -> W_img5[k][j] ; else W_obs3[k][j-1024]
__global__ void kWD(const float* __restrict__ W5, const float* __restrict__ Wo3,
                    float* __restrict__ WDm) {
    int k = blockIdx.x;  // 0..599
    for (int j = threadIdx.x; j < 2048; j += blockDim.x) {
        float v = (j < 1024) ? W5[(size_t)k * 1024 + j] : Wo3[(size_t)k * 1024 + (j - 1024)];
        WDm[(size_t)j * 600 + k] = v;
    }
}

// ---------------- embed precompute: embPre[t][j][b] = b_obs1[j] + sum_k e[b,t,k]*Wo1[600+k][j]
__global__ __launch_bounds__(512) void kPemb(const float* __restrict__ embed,
                                             const float* __restrict__ Wo1,
                                             const float* __restrict__ bo1,
                                             float* __restrict__ embPre) {
    int bid = blockIdx.x;  // t*40 + bg*10 + jg
    int jg = bid % 10;
    int r = bid / 10;
    int bg = r & 3;
    int t = r >> 2;
    int tid = threadIdx.x;
    int lane = tid & 63;
    int wid = __builtin_amdgcn_readfirstlane(tid >> 6);
    int b0 = bg * 64;
    int j0 = jg * 64 + wid * 8;
    bool active = (j0 < 600);
    __shared__ float tile[64 * 129];
    float acc[8] = {0, 0, 0, 0, 0, 0, 0, 0};
    for (int kc = 0; kc < EMB; kc += 128) {
        __syncthreads();
        for (int ii = tid; ii < 64 * 128; ii += 512) {
            int i = ii >> 7, k = ii & 127;
            tile[i * 129 + k] = embed[((size_t)(b0 + i) * T + t) * EMB + kc + k];
        }
        __syncthreads();
        if (active) {
            const float* wbase = Wo1 + (size_t)(600 + kc) * 600 + j0;
#pragma unroll 4
            for (int k = 0; k < 128; ++k) {
                float v = tile[lane * 129 + k];
                float4 wa = *(const float4*)(wbase + (size_t)k * 600);
                float4 wb = *(const float4*)(wbase + (size_t)k * 600 + 4);
                acc[0] += v * wa.x; acc[1] += v * wa.y; acc[2] += v * wa.z; acc[3] += v * wa.w;
                acc[4] += v * wb.x; acc[5] += v * wb.y; acc[6] += v * wb.z; acc[7] += v * wb.w;
            }
        }
    }
    if (active) {
#pragma unroll
        for (int c = 0; c < 8; ++c)
            embPre[((size_t)t * 600 + j0 + c) * B + b0 + lane] = acc[c] + bo1[j0 + c];
    }
}

// ---------------- stage A: xT[h][b] = elu(b1 + action part + one-hot gather-sum)
__global__ __launch_bounds__(256) void kA(const float* __restrict__ act,
                                          const float* __restrict__ W1,
                                          const float* __restrict__ b1,
                                          const int* __restrict__ idxB,
                                          float* __restrict__ xT, int t, int first) {
    int b = blockIdx.x, tid = threadIdx.x;
    __shared__ float sa[ACTN];
    __shared__ int si[S];
    if (tid < ACTN) sa[tid] = act[((size_t)b * T + t) * ACTN + tid];
    if (!first && tid < S) si[tid] = idxB[b * S + tid];
    __syncthreads();
    for (int h = tid; h < HID; h += 256) {
        float a = b1[h];
#pragma unroll
        for (int k = 0; k < ACTN; ++k) a += sa[k] * W1[(size_t)(SFN + k) * HID + h];
        if (!first) {
#pragma unroll 8
            for (int s = 0; s < S; ++s) a += W1[(size_t)(s * DD + si[s]) * HID + h];
        }
        xT[(size_t)h * B + b] = elu1(a);
    }
}

// ---------------- stage B: fused GRU cell, writes deter_n (carry + output)
__global__ __launch_bounds__(512) void kB(const float* __restrict__ xT,
                                          const float* __restrict__ dPrev,
                                          const float* __restrict__ WBm,
                                          const float* __restrict__ b_in,
                                          const float* __restrict__ b_rec,
                                          float* __restrict__ dNext,
                                          float* __restrict__ out, int t) {
    int tid = threadIdx.x, lane = tid & 63;
    int wid = __builtin_amdgcn_readfirstlane(tid >> 6);
    int jg, rg;
    if (!jgMap(blockIdx.x, jg, rg)) return;          // XCD-pinned slice
    int j = jg * 8 + wid;                            // 0..599
    int b = rg * 64 + lane;
    const float* w = WBm + (size_t)j * 3600;
    float az = 0, ar = 0, ax = 0, ah = 0;
#pragma unroll 2
    for (int k = 0; k < 600; k += 4) {
        float4 wa = *(const float4*)(w + 3 * k);
        float4 wb = *(const float4*)(w + 3 * k + 4);
        float4 wc = *(const float4*)(w + 3 * k + 8);
        float x0 = xT[(size_t)(k + 0) * B + b];
        float x1 = xT[(size_t)(k + 1) * B + b];
        float x2 = xT[(size_t)(k + 2) * B + b];
        float x3 = xT[(size_t)(k + 3) * B + b];
        az += x0 * wa.x + x1 * wa.w + x2 * wb.z + x3 * wc.y;
        ar += x0 * wa.y + x1 * wb.x + x2 * wb.w + x3 * wc.z;
        ax += x0 * wa.z + x1 * wb.y + x2 * wc.x + x3 * wc.w;
    }
    const float* w2 = w + 1800;
#pragma unroll 2
    for (int k = 0; k < 600; k += 4) {
        float4 wa = *(const float4*)(w2 + 3 * k);
        float4 wb = *(const float4*)(w2 + 3 * k + 4);
        float4 wc = *(const float4*)(w2 + 3 * k + 8);
        float x0 = dPrev[(size_t)(k + 0) * B + b];
        float x1 = dPrev[(size_t)(k + 1) * B + b];
        float x2 = dPrev[(size_t)(k + 2) * B + b];
        float x3 = dPrev[(size_t)(k + 3) * B + b];
        az += x0 * wa.x + x1 * wa.w + x2 * wb.z + x3 * wc.y;
        ar += x0 * wa.y + x1 * wb.x + x2 * wb.w + x3 * wc.z;
        ah += x0 * wa.z + x1 * wb.y + x2 * wc.x + x3 * wc.w;
    }
    float dp = dPrev[(size_t)j * B + b];
    float z = sigm(az + b_in[j] + b_rec[j]);
    float rr = sigm(ar + b_in[600 + j] + b_rec[600 + j]);
    float cand = tanhf(ax + b_in[1200 + j] + rr * (ah + b_rec[1200 + j]));
    float dn = z * dp + (1.f - z) * cand;
    dNext[(size_t)j * B + b] = dn;
    out[((size_t)b * T + t) * OUTF + 2 * SFN + j] = dn;
}

// ---------------- stage C: y = elu(d @ Wimg2 + b2) ; o = elu(d @ Wobs1_det + embPre)
__global__ __launch_bounds__(512) void kC(const float* __restrict__ dT,
                                          const float* __restrict__ WCm,
                                          const float* __restrict__ b2,
                                          const float* __restrict__ embPre,
                                          float* __restrict__ yoT, int t) {
    int tid = threadIdx.x, lane = tid & 63;
    int wid = __builtin_amdgcn_readfirstlane(tid >> 6);
    int jg, rg;
    if (!jgMap(blockIdx.x, jg, rg)) return;          // XCD-pinned slice
    int j0 = jg * 16 + wid * 2;                      // 0..1198
    int b = rg * 64 + lane;
    const float* w0 = WCm + (size_t)j0 * 600;
    const float* w1 = w0 + 600;
    float a0 = 0, a1 = 0;
#pragma unroll 2
    for (int k = 0; k < 600; k += 4) {
        float4 p = *(const float4*)(w0 + k);
        float4 q = *(const float4*)(w1 + k);
        float v0 = dT[(size_t)(k + 0) * B + b];
        float v1 = dT[(size_t)(k + 1) * B + b];
        float v2 = dT[(size_t)(k + 2) * B + b];
        float v3 = dT[(size_t)(k + 3) * B + b];
        a0 += v0 * p.x + v1 * p.y + v2 * p.z + v3 * p.w;
        a1 += v0 * q.x + v1 * q.y + v2 * q.z + v3 * q.w;
    }
    if (j0 < 600) {
        yoT[(size_t)j0 * B + b] = elu1(a0 + b2[j0]);
        yoT[(size_t)(j0 + 1) * B + b] = elu1(a1 + b2[j0 + 1]);
    } else {
        int je = j0 - 600;
        yoT[(size_t)j0 * B + b] = elu1(a0 + embPre[((size_t)t * 600 + je) * B + b]);
        yoT[(size_t)(j0 + 1) * B + b] = elu1(a1 + embPre[((size_t)t * 600 + je + 1) * B + b]);
    }
}

// ---------------- stage D: logits + gumbel argmax + one-hot + output writes
__global__ __launch_bounds__(512) void kD(const float* __restrict__ yoT,
                                          const float* __restrict__ WDm,
                                          const float* __restrict__ b5,
                                          const float* __restrict__ bo3,
                                          const float* __restrict__ gImg,
                                          const float* __restrict__ gObs,
                                          float* __restrict__ out,
                                          int* __restrict__ idxB, int t) {
    int tid = threadIdx.x, lane = tid & 63;
    int wid = __builtin_amdgcn_readfirstlane(tid >> 6);
    // XCD-pinned: xcd = bid&7 owns 8 fixed sg slices; all 4 rg replicas same XCD.
    int xcd = blockIdx.x & 7, slot = blockIdx.x >> 3;   // grid = 256
    int sg = xcd * 8 + (slot & 7);                      // 0..63 (32 prior, 32 post)
    int rg = slot >> 3;                                 // 0..3
    int post = (sg >= 32) ? 1 : 0;
    int s = post ? sg - 32 : sg;
    int b = rg * 64 + lane;
    int dloc = wid * 4;
    int jglob = post * SFN + s * DD + dloc;
    const float* src = yoT + (post ? (size_t)600 * B : 0);
    const float* w0 = WDm + (size_t)jglob * 600;
    const float* w1 = w0 + 600;
    const float* w2 = w0 + 1200;
    const float* w3 = w0 + 1800;
    float a0 = 0, a1 = 0, a2 = 0, a3 = 0;
#pragma unroll 2
    for (int k = 0; k < 600; k += 4) {
        float4 p0 = *(const float4*)(w0 + k);
        float4 p1 = *(const float4*)(w1 + k);
        float4 p2 = *(const float4*)(w2 + k);
        float4 p3 = *(const float4*)(w3 + k);
        float v0 = src[(size_t)(k + 0) * B + b];
        float v1 = src[(size_t)(k + 1) * B + b];
        float v2 = src[(size_t)(k + 2) * B + b];
        float v3 = src[(size_t)(k + 3) * B + b];
        a0 += v0 * p0.x + v1 * p0.y + v2 * p0.z + v3 * p0.w;
        a1 += v0 * p1.x + v1 * p1.y + v2 * p1.z + v3 * p1.w;
        a2 += v0 * p2.x + v1 * p2.y + v2 * p2.z + v3 * p2.w;
        a3 += v0 * p3.x + v1 * p3.y + v2 * p3.z + v3 * p3.w;
    }
    const float* bias = post ? (bo3 + s * DD) : (b5 + s * DD);
    const float* g = (post ? gObs : gImg) + ((size_t)b * T + t) * SFN + s * DD;
    size_t obase = ((size_t)b * T + t) * OUTF;
    size_t lbase = obase + (post ? 0 : (2 * SFN + DET)) + s * DD;  // logit region
    float vals[4];
    float accs[4] = {a0, a1, a2, a3};
#pragma unroll
    for (int c = 0; c < 4; ++c) {
        float lg = accs[c] + bias[dloc + c];
        out[lbase + dloc + c] = lg;
        vals[c] = lg + g[dloc + c];
    }
    float bm = vals[0];
    int bi = dloc;
#pragma unroll
    for (int c = 1; c < 4; ++c)
        if (vals[c] > bm) { bm = vals[c]; bi = dloc + c; }
    __shared__ float sm[8 * 64];
    __shared__ int sx[8 * 64];
    sm[wid * 64 + lane] = bm;
    sx[wid * 64 + lane] = bi;
    __syncthreads();
    float best = sm[lane];
    int bd = sx[lane];
#pragma unroll
    for (int w = 1; w < 8; ++w) {
        float v = sm[w * 64 + lane];
        if (v > best) { best = v; bd = sx[w * 64 + lane]; }
    }
    size_t sbase = obase + (post ? SFN : (3 * SFN + DET)) + s * DD;  // one-hot region
#pragma unroll
    for (int c = 0; c < 4; ++c)
        out[sbase + dloc + c] = (dloc + c == bd) ? 1.f : 0.f;
    if (post && wid == 0) idxB[b * S + s] = bd;
}

}  // namespace

extern "C" void kernel_launch(void* const* d_in, const int* in_sizes, int n_in,
                              void* d_out, int out_size, void* d_ws, size_t ws_size,
                              hipStream_t stream) {
    const float* action = (const float*)d_in[0];
    const float* embed  = (const float*)d_in[1];
    const float* gImg   = (const float*)d_in[2];
    const float* gObs   = (const float*)d_in[3];
    const float* W1     = (const float*)d_in[4];
    const float* b1     = (const float*)d_in[5];
    const float* Wx     = (const float*)d_in[6];
    const float* Wh     = (const float*)d_in[7];
    const float* b_in   = (const float*)d_in[8];
    const float* b_rec  = (const float*)d_in[9];
    const float* W2     = (const float*)d_in[10];
    const float* b2     = (const float*)d_in[11];
    const float* W5     = (const float*)d_in[12];
    const float* b5     = (const float*)d_in[13];
    const float* Wo1    = (const float*)d_in[14];
    const float* bo1    = (const float*)d_in[15];
    const float* Wo3    = (const float*)d_in[16];
    const float* bo3    = (const float*)d_in[17];
    float* out = (float*)d_out;

    float* ws = (float*)d_ws;
    float* WBm    = ws;                  // 600*1200*3 = 2,160,000 f
    float* WCm    = WBm + 2160000;       // 1200*600   =   720,000 f
    float* WDm    = WCm + 720000;        // 2048*600   = 1,228,800 f
    float* embPre = WDm + 1228800;       // 64*600*256 = 9,830,400 f
    float* xT     = embPre + 9830400;    // 600*256
    float* dA     = xT + 153600;
    float* dB     = dA + 153600;
    float* yoT    = dB + 153600;         // 1200*256
    int*   idxB   = (int*)(yoT + 307200);

    hipMemsetAsync(dA, 0, 153600 * sizeof(float), stream);  // deter0 = zeros
    kWB<<<1200, 256, 0, stream>>>(Wx, Wh, WBm);
    kWC<<<600, 256, 0, stream>>>(W2, Wo1, WCm);
    kWD<<<600, 256, 0, stream>>>(W5, Wo3, WDm);
    kPemb<<<2560, 512, 0, stream>>>(embed, Wo1, bo1, embPre);

    for (int t = 0; t < T; ++t) {
        float* dP = (t & 1) ? dB : dA;
        float* dN = (t & 1) ? dA : dB;
        kA<<<256, 256, 0, stream>>>(action, W1, b1, idxB, xT, t, t == 0 ? 1 : 0);
        kB<<<320, 512, 0, stream>>>(xT, dP, WBm, b_in, b_rec, dN, out, t);
        kC<<<320, 512, 0, stream>>>(dN, WCm, b2, embPre, yoT, t);
        kD<<<256, 512, 0, stream>>>(yoT, WDm, b5, bo3, gImg, gObs, out, idxB, t);
    }
}

// Round 2
// 9134.975 us; speedup vs baseline: 1.1558x; 1.1295x over previous
//
#include <hip/hip_runtime.h>
#include <math.h>

namespace {

constexpr int B = 256, T = 64, ACTN = 6, EMB = 1024;
constexpr int S = 32, DD = 32, SFN = 1024;   // stoch groups, classes, flat
constexpr int DET = 600, HID = 600;
constexpr int OUTF = 4 * SFN + DET;          // 4696
constexpr int KC = 100;                      // LDS activation chunk rows

__device__ __forceinline__ float elu1(float x) { return x > 0.f ? x : expm1f(x); }
__device__ __forceinline__ float sigm(float x) { return 1.f / (1.f + expf(-x)); }

// XCD-pinned jg mapping: 75 jg groups split 10,10,10,9,9,9,9,9 across 8 XCDs.
__device__ __forceinline__ bool jgMap(int bid, int& jg, int& rg) {
    int xcd = bid & 7, slot = bid >> 3;   // grid = 320
    int jgLocal = slot >> 2;
    rg = slot & 3;
    int cnt = (xcd < 3) ? 10 : 9;
    if (jgLocal >= cnt) return false;
    jg = ((xcd < 3) ? xcd * 10 : 30 + (xcd - 3) * 9) + jgLocal;
    return true;
}

// Cooperative stage of two [KC x 64] fp32 activation tiles (1024 threads).
__device__ __forceinline__ void stage2(const float* __restrict__ sA,
                                       const float* __restrict__ sB,
                                       float* __restrict__ tA,
                                       float* __restrict__ tB,
                                       int b0, int tid) {
    for (int idx = tid; idx < KC * 16 * 2; idx += 1024) {
        int hf = idx >= KC * 16;
        int i2 = hf ? (idx - KC * 16) : idx;
        int kk = i2 >> 4, q = (i2 & 15) << 2;
        float4 v = *(const float4*)((hf ? sB : sA) + (size_t)kk * B + b0 + q);
        float* d = (hf ? tB : tA) + kk * 64 + q;
        d[0] = v.x; d[1] = v.y; d[2] = v.z; d[3] = v.w;
    }
}

// ---------------- weight prep: fused/transposed layouts ----------------
__global__ void kWB(const float* __restrict__ Wx, const float* __restrict__ Wh,
                    float* __restrict__ WBm) {
    int k = blockIdx.x;  // 0..1199
    const float* src = (k < 600) ? (Wx + (size_t)k * 1800) : (Wh + (size_t)(k - 600) * 1800);
    for (int j = threadIdx.x; j < 600; j += blockDim.x) {
        size_t o = ((size_t)j * 1200 + k) * 3;
        WBm[o + 0] = src[j];
        WBm[o + 1] = src[600 + j];
        WBm[o + 2] = src[1200 + j];
    }
}

__global__ void kWC(const float* __restrict__ W2, const float* __restrict__ Wo1,
                    float* __restrict__ WCm) {
    int k = blockIdx.x;  // 0..599
    for (int j = threadIdx.x; j < 1200; j += blockDim.x) {
        float v = (j < 600) ? W2[(size_t)k * 600 + j] : Wo1[(size_t)k * 600 + (j - 600)];
        WCm[(size_t)j * 600 + k] = v;
    }
}

__global__ void kWD(const float* __restrict__ W5, const float* __restrict__ Wo3,
                    float* __restrict__ WDm) {
    int k = blockIdx.x;  // 0..599
    for (int j = threadIdx.x; j < 2048; j += blockDim.x) {
        float v = (j < 1024) ? W5[(size_t)k * 1024 + j] : Wo3[(size_t)k * 1024 + (j - 1024)];
        WDm[(size_t)j * 600 + k] = v;
    }
}

// ---------------- embed precompute (unchanged) ----------------
__global__ __launch_bounds__(512) void kPemb(const float* __restrict__ embed,
                                             const float* __restrict__ Wo1,
                                             const float* __restrict__ bo1,
                                             float* __restrict__ embPre) {
    int bid = blockIdx.x;  // t*40 + bg*10 + jg
    int jg = bid % 10;
    int r = bid / 10;
    int bg = r & 3;
    int t = r >> 2;
    int tid = threadIdx.x;
    int lane = tid & 63;
    int wid = __builtin_amdgcn_readfirstlane(tid >> 6);
    int b0 = bg * 64;
    int j0 = jg * 64 + wid * 8;
    bool active = (j0 < 600);
    __shared__ float tile[64 * 129];
    float acc[8] = {0, 0, 0, 0, 0, 0, 0, 0};
    for (int kc = 0; kc < EMB; kc += 128) {
        __syncthreads();
        for (int ii = tid; ii < 64 * 128; ii += 512) {
            int i = ii >> 7, k = ii & 127;
            tile[i * 129 + k] = embed[((size_t)(b0 + i) * T + t) * EMB + kc + k];
        }
        __syncthreads();
        if (active) {
            const float* wbase = Wo1 + (size_t)(600 + kc) * 600 + j0;
#pragma unroll 4
            for (int k = 0; k < 128; ++k) {
                float v = tile[lane * 129 + k];
                float4 wa = *(const float4*)(wbase + (size_t)k * 600);
                float4 wb = *(const float4*)(wbase + (size_t)k * 600 + 4);
                acc[0] += v * wa.x; acc[1] += v * wa.y; acc[2] += v * wa.z; acc[3] += v * wa.w;
                acc[4] += v * wb.x; acc[5] += v * wb.y; acc[6] += v * wb.z; acc[7] += v * wb.w;
            }
        }
    }
    if (active) {
#pragma unroll
        for (int c = 0; c < 8; ++c)
            embPre[((size_t)t * 600 + j0 + c) * B + b0 + lane] = acc[c] + bo1[j0 + c];
    }
}

// ---------------- stage A (unchanged) ----------------
__global__ __launch_bounds__(256) void kA(const float* __restrict__ act,
                                          const float* __restrict__ W1,
                                          const float* __restrict__ b1,
                                          const int* __restrict__ idxB,
                                          float* __restrict__ xT, int t, int first) {
    int b = blockIdx.x, tid = threadIdx.x;
    __shared__ float sa[ACTN];
    __shared__ int si[S];
    if (tid < ACTN) sa[tid] = act[((size_t)b * T + t) * ACTN + tid];
    if (!first && tid < S) si[tid] = idxB[b * S + tid];
    __syncthreads();
    for (int h = tid; h < HID; h += 256) {
        float a = b1[h];
#pragma unroll
        for (int k = 0; k < ACTN; ++k) a += sa[k] * W1[(size_t)(SFN + k) * HID + h];
        if (!first) {
#pragma unroll 8
            for (int s = 0; s < S; ++s) a += W1[(size_t)(s * DD + si[s]) * HID + h];
        }
        xT[(size_t)h * B + b] = elu1(a);
    }
}

// ---------------- stage B: GRU cell. 16 waves = 8 j x 2 k-halves, LDS-staged acts.
__global__ __launch_bounds__(1024, 8) void kB(const float* __restrict__ xT,
                                              const float* __restrict__ dPrev,
                                              const float* __restrict__ WBm,
                                              const float* __restrict__ b_in,
                                              const float* __restrict__ b_rec,
                                              float* __restrict__ dNext,
                                              float* __restrict__ out, int t) {
    int jg, rg;
    if (!jgMap(blockIdx.x, jg, rg)) return;
    int tid = threadIdx.x, lane = tid & 63;
    int wid = __builtin_amdgcn_readfirstlane(tid >> 6);  // 0..15
    int ws = wid & 7, kh = wid >> 3;                     // j-slot, array-half
    int j = jg * 8 + ws;
    int b0 = rg * 64;
    int b = b0 + lane;
    __shared__ float tA[KC * 64];        // xT chunk (kh=0)
    __shared__ float tB[KC * 64];        // dPrev chunk (kh=1)
    __shared__ float part[8][3][64];
    const float* wbase = WBm + (size_t)j * 3600 + (kh ? 1800 : 0);
    float a0 = 0, a1 = 0, a2 = 0;        // z, r, (x-h or d-h)
    for (int c = 0; c < 600; c += KC) {
        stage2(xT + (size_t)c * B, dPrev + (size_t)c * B, tA, tB, b0, tid);
        __syncthreads();
        const float* w = wbase + 3 * c;
        const float* tl = kh ? tB : tA;
#pragma unroll 2
        for (int kk = 0; kk < KC; kk += 4) {
            float4 wa = *(const float4*)(w + 3 * kk);
            float4 wb = *(const float4*)(w + 3 * kk + 4);
            float4 wc = *(const float4*)(w + 3 * kk + 8);
            float x0 = tl[(kk + 0) * 64 + lane];
            float x1 = tl[(kk + 1) * 64 + lane];
            float x2 = tl[(kk + 2) * 64 + lane];
            float x3 = tl[(kk + 3) * 64 + lane];
            a0 += x0 * wa.x + x1 * wa.w + x2 * wb.z + x3 * wc.y;
            a1 += x0 * wa.y + x1 * wb.x + x2 * wb.w + x3 * wc.z;
            a2 += x0 * wa.z + x1 * wb.y + x2 * wc.x + x3 * wc.w;
        }
        __syncthreads();
    }
    if (kh) {
        part[ws][0][lane] = a0;
        part[ws][1][lane] = a1;
        part[ws][2][lane] = a2;
    }
    __syncthreads();
    if (!kh) {
        float az = a0 + part[ws][0][lane];
        float ar = a1 + part[ws][1][lane];
        float ax = a2;                   // x-part of h
        float ah = part[ws][2][lane];    // d-part of h
        float dp = dPrev[(size_t)j * B + b];
        float z = sigm(az + b_in[j] + b_rec[j]);
        float rr = sigm(ar + b_in[600 + j] + b_rec[600 + j]);
        float cand = tanhf(ax + b_in[1200 + j] + rr * (ah + b_rec[1200 + j]));
        float dn = z * dp + (1.f - z) * cand;
        dNext[(size_t)j * B + b] = dn;
        out[((size_t)b * T + t) * OUTF + 2 * SFN + j] = dn;
    }
}

// ---------------- stage C: 16 waves = 8 (j-pair) x 2 k-halves, LDS-staged dT.
__global__ __launch_bounds__(1024, 8) void kC(const float* __restrict__ dT,
                                              const float* __restrict__ WCm,
                                              const float* __restrict__ b2,
                                              const float* __restrict__ embPre,
                                              float* __restrict__ yoT, int t) {
    int jg, rg;
    if (!jgMap(blockIdx.x, jg, rg)) return;
    int tid = threadIdx.x, lane = tid & 63;
    int wid = __builtin_amdgcn_readfirstlane(tid >> 6);
    int ws = wid & 7, kh = wid >> 3;
    int j0 = jg * 16 + ws * 2;           // 0..1198
    int b0 = rg * 64;
    int b = b0 + lane;
    __shared__ float tA[KC * 64];        // dT rows [c, c+KC)       (kh=0)
    __shared__ float tB[KC * 64];        // dT rows [300+c, 300+c+KC) (kh=1)
    __shared__ float part[8][2][64];
    const float* w0 = WCm + (size_t)j0 * 600 + kh * 300;
    const float* w1 = w0 + 600;
    float a0 = 0, a1 = 0;
    for (int c = 0; c < 300; c += KC) {
        stage2(dT + (size_t)c * B, dT + (size_t)(300 + c) * B, tA, tB, b0, tid);
        __syncthreads();
        const float* tl = kh ? tB : tA;
#pragma unroll 2
        for (int kk = 0; kk < KC; kk += 4) {
            float4 p = *(const float4*)(w0 + c + kk);
            float4 q = *(const float4*)(w1 + c + kk);
            float v0 = tl[(kk + 0) * 64 + lane];
            float v1 = tl[(kk + 1) * 64 + lane];
            float v2 = tl[(kk + 2) * 64 + lane];
            float v3 = tl[(kk + 3) * 64 + lane];
            a0 += v0 * p.x + v1 * p.y + v2 * p.z + v3 * p.w;
            a1 += v0 * q.x + v1 * q.y + v2 * q.z + v3 * q.w;
        }
        __syncthreads();
    }
    if (kh) {
        part[ws][0][lane] = a0;
        part[ws][1][lane] = a1;
    }
    __syncthreads();
    if (!kh) {
        float s0 = a0 + part[ws][0][lane];
        float s1 = a1 + part[ws][1][lane];
        if (j0 < 600) {
            yoT[(size_t)j0 * B + b] = elu1(s0 + b2[j0]);
            yoT[(size_t)(j0 + 1) * B + b] = elu1(s1 + b2[j0 + 1]);
        } else {
            int je = j0 - 600;
            yoT[(size_t)j0 * B + b] = elu1(s0 + embPre[((size_t)t * 600 + je) * B + b]);
            yoT[(size_t)(j0 + 1) * B + b] = elu1(s1 + embPre[((size_t)t * 600 + je + 1) * B + b]);
        }
    }
}

// ---------------- stage D: 16 waves = 8 (4-class) x 2 k-halves, LDS-staged yoT.
__global__ __launch_bounds__(1024, 4) void kD(const float* __restrict__ yoT,
                                              const float* __restrict__ WDm,
                                              const float* __restrict__ b5,
                                              const float* __restrict__ bo3,
                                              const float* __restrict__ gImg,
                                              const float* __restrict__ gObs,
                                              float* __restrict__ out,
                                              int* __restrict__ idxB, int t) {
    int tid = threadIdx.x, lane = tid & 63;
    int wid = __builtin_amdgcn_readfirstlane(tid >> 6);
    int ws = wid & 7, kh = wid >> 3;
    // XCD-pinned: xcd owns 8 fixed sg slices; all 4 rg replicas same XCD. grid=256.
    int xcd = blockIdx.x & 7, slot = blockIdx.x >> 3;
    int sg = xcd * 8 + (slot & 7);        // 0..63 (32 prior, 32 post)
    int rg = slot >> 3;                   // 0..3
    int post = (sg >= 32) ? 1 : 0;
    int s = post ? sg - 32 : sg;
    int b0 = rg * 64;
    int b = b0 + lane;
    int dloc = ws * 4;
    int jglob = post * SFN + s * DD + dloc;
    const float* src = yoT + (post ? (size_t)600 * B : 0);
    __shared__ float tA[KC * 64];
    __shared__ float tB[KC * 64];
    __shared__ float part[8][4][64];
    __shared__ float sm[8 * 64];
    __shared__ int sx[8 * 64];
    const float* w0 = WDm + (size_t)jglob * 600 + kh * 300;
    const float* w1 = w0 + 600;
    const float* w2 = w0 + 1200;
    const float* w3 = w0 + 1800;
    float a0 = 0, a1 = 0, a2 = 0, a3 = 0;
    for (int c = 0; c < 300; c += KC) {
        stage2(src + (size_t)c * B, src + (size_t)(300 + c) * B, tA, tB, b0, tid);
        __syncthreads();
        const float* tl = kh ? tB : tA;
#pragma unroll 2
        for (int kk = 0; kk < KC; kk += 4) {
            float4 p0 = *(const float4*)(w0 + c + kk);
            float4 p1 = *(const float4*)(w1 + c + kk);
            float4 p2 = *(const float4*)(w2 + c + kk);
            float4 p3 = *(const float4*)(w3 + c + kk);
            float v0 = tl[(kk + 0) * 64 + lane];
            float v1 = tl[(kk + 1) * 64 + lane];
            float v2 = tl[(kk + 2) * 64 + lane];
            float v3 = tl[(kk + 3) * 64 + lane];
            a0 += v0 * p0.x + v1 * p0.y + v2 * p0.z + v3 * p0.w;
            a1 += v0 * p1.x + v1 * p1.y + v2 * p1.z + v3 * p1.w;
            a2 += v0 * p2.x + v1 * p2.y + v2 * p2.z + v3 * p2.w;
            a3 += v0 * p3.x + v1 * p3.y + v2 * p3.z + v3 * p3.w;
        }
        __syncthreads();
    }
    if (kh) {
        part[ws][0][lane] = a0;
        part[ws][1][lane] = a1;
        part[ws][2][lane] = a2;
        part[ws][3][lane] = a3;
    }
    __syncthreads();
    if (!kh) {
        float accs[4] = {a0 + part[ws][0][lane], a1 + part[ws][1][lane],
                         a2 + part[ws][2][lane], a3 + part[ws][3][lane]};
        const float* bias = post ? (bo3 + s * DD) : (b5 + s * DD);
        const float* g = (post ? gObs : gImg) + ((size_t)b * T + t) * SFN + s * DD;
        size_t obase = ((size_t)b * T + t) * OUTF;
        size_t lbase = obase + (post ? 0 : (2 * SFN + DET)) + s * DD;
        float vals[4];
#pragma unroll
        for (int c = 0; c < 4; ++c) {
            float lg = accs[c] + bias[dloc + c];
            out[lbase + dloc + c] = lg;
            vals[c] = lg + g[dloc + c];
        }
        float bm = vals[0];
        int bi = dloc;
#pragma unroll
        for (int c = 1; c < 4; ++c)
            if (vals[c] > bm) { bm = vals[c]; bi = dloc + c; }
        sm[ws * 64 + lane] = bm;
        sx[ws * 64 + lane] = bi;
    }
    __syncthreads();
    if (!kh) {
        float best = sm[lane];
        int bd = sx[lane];
#pragma unroll
        for (int w = 1; w < 8; ++w) {
            float v = sm[w * 64 + lane];
            if (v > best) { best = v; bd = sx[w * 64 + lane]; }
        }
        int post2 = post;
        size_t obase = ((size_t)b * T + t) * OUTF;
        size_t sbase = obase + (post2 ? SFN : (3 * SFN + DET)) + s * DD;
#pragma unroll
        for (int c = 0; c < 4; ++c)
            out[sbase + dloc + c] = (dloc + c == bd) ? 1.f : 0.f;
        if (post2 && ws == 0) idxB[b * S + s] = bd;
    }
}

}  // namespace

extern "C" void kernel_launch(void* const* d_in, const int* in_sizes, int n_in,
                              void* d_out, int out_size, void* d_ws, size_t ws_size,
                              hipStream_t stream) {
    const float* action = (const float*)d_in[0];
    const float* embed  = (const float*)d_in[1];
    const float* gImg   = (const float*)d_in[2];
    const float* gObs   = (const float*)d_in[3];
    const float* W1     = (const float*)d_in[4];
    const float* b1     = (const float*)d_in[5];
    const float* Wx     = (const float*)d_in[6];
    const float* Wh     = (const float*)d_in[7];
    const float* b_in   = (const float*)d_in[8];
    const float* b_rec  = (const float*)d_in[9];
    const float* W2     = (const float*)d_in[10];
    const float* b2     = (const float*)d_in[11];
    const float* W5     = (const float*)d_in[12];
    const float* b5     = (const float*)d_in[13];
    const float* Wo1    = (const float*)d_in[14];
    const float* bo1    = (const float*)d_in[15];
    const float* Wo3    = (const float*)d_in[16];
    const float* bo3    = (const float*)d_in[17];
    float* out = (float*)d_out;

    float* ws = (float*)d_ws;
    float* WBm    = ws;                  // 600*1200*3 = 2,160,000 f
    float* WCm    = WBm + 2160000;       // 1200*600   =   720,000 f
    float* WDm    = WCm + 720000;        // 2048*600   = 1,228,800 f
    float* embPre = WDm + 1228800;       // 64*600*256 = 9,830,400 f
    float* xT     = embPre + 9830400;    // 600*256
    float* dA     = xT + 153600;
    float* dB     = dA + 153600;
    float* yoT    = dB + 153600;         // 1200*256
    int*   idxB   = (int*)(yoT + 307200);

    hipMemsetAsync(dA, 0, 153600 * sizeof(float), stream);  // deter0 = zeros
    kWB<<<1200, 256, 0, stream>>>(Wx, Wh, WBm);
    kWC<<<600, 256, 0, stream>>>(W2, Wo1, WCm);
    kWD<<<600, 256, 0, stream>>>(W5, Wo3, WDm);
    kPemb<<<2560, 512, 0, stream>>>(embed, Wo1, bo1, embPre);

    for (int t = 0; t < T; ++t) {
        float* dP = (t & 1) ? dB : dA;
        float* dN = (t & 1) ? dA : dB;
        kA<<<256, 256, 0, stream>>>(action, W1, b1, idxB, xT, t, t == 0 ? 1 : 0);
        kB<<<320, 1024, 0, stream>>>(xT, dP, WBm, b_in, b_rec, dN, out, t);
        kC<<<320, 1024, 0, stream>>>(dN, WCm, b2, embPre, yoT, t);
        kD<<<256, 1024, 0, stream>>>(yoT, WDm, b5, bo3, gImg, gObs, out, idxB, t);
    }
}